// Round 1
// baseline (347.775 us; speedup 1.0000x reference)
//
#include <hip/hip_runtime.h>
#include <cmath>

// Per-class constants: w[c][j] = normalized (table[c][j]+eps); cst[c] = sum_j w*log(w).
// Passed by value (128B of kernarg) — computed host-side in double each launch.
struct KLConsts {
    float w[4][7];
    float cst[4];
};

__global__ __launch_bounds__(256) void kl_rows(
    const float* __restrict__ logits,   // [B,7]
    const int*   __restrict__ tgt,      // [B]
    double*      __restrict__ acc,      // [1] workspace accumulator (pre-zeroed)
    int B, KLConsts kc)
{
    int i = blockIdx.x * blockDim.x + threadIdx.x;
    float local = 0.0f;
    if (i < B) {
        int t = tgt[i];
        int idx = ((unsigned)t <= 2u) ? t : 3;   // outside {0,1,2} -> uniform row

        const float* x = logits + (size_t)i * 7;
        float v[7];
        #pragma unroll
        for (int j = 0; j < 7; ++j) v[j] = x[j];

        float m = v[0];
        #pragma unroll
        for (int j = 1; j < 7; ++j) m = fmaxf(m, v[j]);

        float e[7];
        float Z = 0.0f;
        #pragma unroll
        for (int j = 0; j < 7; ++j) { e[j] = __expf(v[j] - m); Z += e[j]; }
        float invZ = 1.0f / Z;

        const float* w = kc.w[idx];
        float s = 0.0f;
        #pragma unroll
        for (int j = 0; j < 7; ++j) {
            float p = e[j] * invZ;               // softmax prob
            s += w[j] * __logf(p + 1e-8f);       // sum w * log(p + eps)
        }
        local = kc.cst[idx] - s;                 // sum w*(log w - log(p+eps))
    }

    // wave (64-lane) reduction
    #pragma unroll
    for (int off = 32; off > 0; off >>= 1)
        local += __shfl_down(local, off, 64);

    __shared__ float smem[4];                    // 256 threads = 4 waves
    int lane = threadIdx.x & 63;
    int wid  = threadIdx.x >> 6;
    if (lane == 0) smem[wid] = local;
    __syncthreads();
    if (threadIdx.x == 0) {
        float bs = smem[0] + smem[1] + smem[2] + smem[3];
        atomicAdd(acc, (double)bs);              // one device-scope atomic per block
    }
}

__global__ void kl_final(const double* __restrict__ acc, float* __restrict__ out, int B)
{
    out[0] = (float)(acc[0] / (double)B);
}

extern "C" void kernel_launch(void* const* d_in, const int* in_sizes, int n_in,
                              void* d_out, int out_size, void* d_ws, size_t ws_size,
                              hipStream_t stream) {
    // d_in[0] = fatigue_logits [B,3]  -- UNUSED by the reference, never read
    const float* emotion = (const float*)d_in[1];   // [B,7] float32
    const int*   targets = (const int*)d_in[2];     // [B]   int32
    float*  out = (float*)d_out;                    // scalar
    double* acc = (double*)d_ws;

    const int B = in_sizes[2];                      // 4,000,000

    // Host-side constant table (double precision, matches reference eps handling)
    static const double T[4][7] = {
        {0.05, 0.02, 0.03, 0.4, 0.05, 0.4, 0.05},
        {0.05, 0.05, 0.05, 0.05, 0.3, 0.05, 0.45},
        {0.1, 0.15, 0.2, 0.02, 0.35, 0.03, 0.15},
        {1.0/7.0, 1.0/7.0, 1.0/7.0, 1.0/7.0, 1.0/7.0, 1.0/7.0, 1.0/7.0},
    };
    const double eps = 1e-8;
    KLConsts kc;
    for (int c = 0; c < 4; ++c) {
        double s = 0.0;
        for (int j = 0; j < 7; ++j) s += T[c][j] + eps;
        double cst = 0.0;
        for (int j = 0; j < 7; ++j) {
            double w = (T[c][j] + eps) / s;
            kc.w[c][j] = (float)w;
            cst += w * std::log(w);
        }
        kc.cst[c] = (float)cst;
    }

    // d_ws is re-poisoned (0xAA) before every timed launch — zero it in-stream.
    hipMemsetAsync(acc, 0, sizeof(double), stream);

    int nblocks = (B + 255) / 256;
    kl_rows<<<nblocks, 256, 0, stream>>>(emotion, targets, acc, B, kc);
    kl_final<<<1, 1, 0, stream>>>(acc, out, B);
}

// Round 2
// 197.126 us; speedup vs baseline: 1.7642x; 1.7642x over previous
//
#include <hip/hip_runtime.h>
#include <cmath>

// Per-class constants: w[c][j] = normalized (table[c][j]+eps); cst[c] = sum_j w*log(w).
struct KLC {
    float w0[7], w1[7], w2[7], w3[7];
    float cst0, cst1, cst2, cst3;
};

__device__ __forceinline__ float row_kl(const float* __restrict__ x, int t, const KLC& kc) {
    int c = ((unsigned)t <= 2u) ? t : 3;

    float m = x[0];
    #pragma unroll
    for (int j = 1; j < 7; ++j) m = fmaxf(m, x[j]);

    float Z = 0.0f;
    #pragma unroll
    for (int j = 0; j < 7; ++j) Z += __expf(x[j] - m);

    // dot(w_c, v) for all 4 classes, branchless select (VALU is idle; selects beat indexed access)
    float d0 = 0.f, d1 = 0.f, d2 = 0.f, d3 = 0.f;
    #pragma unroll
    for (int j = 0; j < 7; ++j) {
        d0 = fmaf(kc.w0[j], x[j], d0);
        d1 = fmaf(kc.w1[j], x[j], d1);
        d2 = fmaf(kc.w2[j], x[j], d2);
        d3 = fmaf(kc.w3[j], x[j], d3);
    }
    float dw = (c == 0) ? d0 : (c == 1) ? d1 : (c == 2) ? d2 : d3;
    float cs = (c == 0) ? kc.cst0 : (c == 1) ? kc.cst1 : (c == 2) ? kc.cst2 : kc.cst3;

    // sum w*(log w - log p) with log p = v - m - logZ  (eps-in-log dropped: error << threshold)
    return cs - dw + m + __logf(Z);
}

__global__ __launch_bounds__(256) void kl_main(
    const float* __restrict__ logits,   // [B,7]
    const int*   __restrict__ tgt,      // [B]
    long long nquad, int rem,
    double* __restrict__ partial,       // [gridDim.x]
    KLC kc)
{
    const float4* __restrict__ lg4 = (const float4*)logits;
    const int4*   __restrict__ tg4 = (const int4*)tgt;

    long long gid    = (long long)blockIdx.x * blockDim.x + threadIdx.x;
    long long stride = (long long)gridDim.x * blockDim.x;

    float local = 0.0f;
    for (long long q = gid; q < nquad; q += stride) {
        // 4 rows = 28 floats = 7 float4 loads; 8 independent loads in flight
        float4 f0 = lg4[q * 7 + 0];
        float4 f1 = lg4[q * 7 + 1];
        float4 f2 = lg4[q * 7 + 2];
        float4 f3 = lg4[q * 7 + 3];
        float4 f4 = lg4[q * 7 + 4];
        float4 f5 = lg4[q * 7 + 5];
        float4 f6 = lg4[q * 7 + 6];
        int4   tq = tg4[q];

        float v[28] = { f0.x, f0.y, f0.z, f0.w,
                        f1.x, f1.y, f1.z, f1.w,
                        f2.x, f2.y, f2.z, f2.w,
                        f3.x, f3.y, f3.z, f3.w,
                        f4.x, f4.y, f4.z, f4.w,
                        f5.x, f5.y, f5.z, f5.w,
                        f6.x, f6.y, f6.z, f6.w };
        int tt[4] = { tq.x, tq.y, tq.z, tq.w };

        #pragma unroll
        for (int r = 0; r < 4; ++r)
            local += row_kl(&v[r * 7], tt[r], kc);
    }

    // remainder rows (B % 4), handled by one thread (B=4M -> rem=0)
    if (blockIdx.x == 0 && threadIdx.x == 0) {
        for (int r = 0; r < rem; ++r) {
            long long row = nquad * 4 + r;
            float x[7];
            #pragma unroll
            for (int j = 0; j < 7; ++j) x[j] = logits[row * 7 + j];
            local += row_kl(x, tgt[row], kc);
        }
    }

    // wave (64) reduction
    #pragma unroll
    for (int off = 32; off > 0; off >>= 1)
        local += __shfl_down(local, off, 64);

    __shared__ float smem[4];
    int lane = threadIdx.x & 63;
    int wid  = threadIdx.x >> 6;
    if (lane == 0) smem[wid] = local;
    __syncthreads();
    if (threadIdx.x == 0)
        partial[blockIdx.x] = (double)(smem[0] + smem[1] + smem[2] + smem[3]);
}

__global__ __launch_bounds__(256) void kl_reduce(
    const double* __restrict__ partial, int nb,
    float* __restrict__ out, int B)
{
    double s = 0.0;
    for (int i = threadIdx.x; i < nb; i += 256) s += partial[i];

    #pragma unroll
    for (int off = 32; off > 0; off >>= 1)
        s += __shfl_down(s, off, 64);

    __shared__ double smem[4];
    int lane = threadIdx.x & 63;
    int wid  = threadIdx.x >> 6;
    if (lane == 0) smem[wid] = s;
    __syncthreads();
    if (threadIdx.x == 0)
        out[0] = (float)((smem[0] + smem[1] + smem[2] + smem[3]) / (double)B);
}

extern "C" void kernel_launch(void* const* d_in, const int* in_sizes, int n_in,
                              void* d_out, int out_size, void* d_ws, size_t ws_size,
                              hipStream_t stream) {
    // d_in[0] = fatigue_logits [B,3] -- unused by the reference, never read
    const float* emotion = (const float*)d_in[1];   // [B,7] float32
    const int*   targets = (const int*)d_in[2];     // [B]   int32 (harness converts int64)
    float*  out     = (float*)d_out;                // scalar
    double* partial = (double*)d_ws;

    const int B = in_sizes[2];                      // 4,000,000
    const long long nquad = B / 4;
    const int rem = B & 3;

    int nb = 1024;                                  // 4 blocks/CU, grid-stride
    if ((size_t)nb * sizeof(double) > ws_size)      // safety clamp
        nb = (int)(ws_size / sizeof(double));

    // Host-side constant table (double precision, matches reference eps handling)
    static const double T[4][7] = {
        {0.05, 0.02, 0.03, 0.4, 0.05, 0.4, 0.05},
        {0.05, 0.05, 0.05, 0.05, 0.3, 0.05, 0.45},
        {0.1, 0.15, 0.2, 0.02, 0.35, 0.03, 0.15},
        {1.0/7.0, 1.0/7.0, 1.0/7.0, 1.0/7.0, 1.0/7.0, 1.0/7.0, 1.0/7.0},
    };
    const double eps = 1e-8;
    KLC kc;
    float* wrows[4] = { kc.w0, kc.w1, kc.w2, kc.w3 };
    float* csts[4]  = { &kc.cst0, &kc.cst1, &kc.cst2, &kc.cst3 };
    for (int c = 0; c < 4; ++c) {
        double s = 0.0;
        for (int j = 0; j < 7; ++j) s += T[c][j] + eps;
        double cst = 0.0;
        for (int j = 0; j < 7; ++j) {
            double w = (T[c][j] + eps) / s;
            wrows[c][j] = (float)w;
            cst += w * std::log(w);
        }
        *csts[c] = (float)cst;
    }

    kl_main<<<nb, 256, 0, stream>>>(emotion, targets, nquad, rem, partial, kc);
    kl_reduce<<<1, 256, 0, stream>>>(partial, nb, out, B);
}